// Round 16
// baseline (80.995 us; speedup 1.0000x reference)
//
#include <hip/hip_runtime.h>

#define B_ 256
#define N_IN 1152
#define N_OUT 10
#define D_OUT 16
#define OJ 160                     // N_OUT * D_OUT
#define SN (B_*OJ)                 // 40960
#define LOG2E 1.44269504088896340736f
#define NPB 16                     // pass23: n's per block
#define NPW 4                      // pass23: n's per wave
#define NSG (N_IN/NPB)             // 72 partial groups for pass2/3
#define NPASSB (NSG*16)            // 1152 pass23 blocks
#define NPB1 32                    // pass1: n's per block (4-n K-packed, bf16-only)
#define NSG1 (N_IN/NPB1)           // 36 partial groups for pass1
#define NP1B (NSG1*16)             // 576 pass1 blocks

typedef __attribute__((ext_vector_type(8))) short bf16x8;
typedef __attribute__((ext_vector_type(4))) float f32x4;

#define NW_ELEMS (N_IN*N_OUT*D_OUT)      // 184320 rows of 8 (W)
#define NX_ELEMS (B_*N_IN)               // 294912 rows of 8 (x)
#define NWB (NW_ELEMS/256)               // 720 W-pack blocks
#define NTILES ((N_IN/16)*(B_/16))       // 1152 x-transpose tiles

// ---- bf16 split helpers (RNE) ----
__device__ __forceinline__ unsigned short f2bf(float f) {
  unsigned u = __float_as_uint(f);
  u += 0x7fffu + ((u >> 16) & 1u);
  return (unsigned short)(u >> 16);
}
__device__ __forceinline__ float bf2f(unsigned short s) {
  return __uint_as_float(((unsigned)s) << 16);
}
__device__ __forceinline__ void split8(const float* p, bf16x8& vh, bf16x8& vl) {
  const float4 a = *(const float4*)p;
  const float4 b = *(const float4*)(p + 4);
  const float w[8] = {a.x,a.y,a.z,a.w,b.x,b.y,b.z,b.w};
#pragma unroll
  for (int e=0;e<8;e++){
    unsigned short hh = f2bf(w[e]);
    vh[e] = (short)hh;
    vl[e] = (short)f2bf(w[e] - bf2f(hh));
  }
}

// ---- inline 8x f32 -> bf16x8 via HW packed cvt (RNE; matches f2bf) ----
__device__ __forceinline__ bf16x8 cvt8(const float* p) {
  const f32x4 a = *(const f32x4*)p;
  const f32x4 b = *(const f32x4*)(p + 4);
  union { unsigned u[4]; bf16x8 v; } r;
  asm("v_cvt_pk_bf16_f32 %0, %1, %2" : "=v"(r.u[0]) : "v"(a[0]), "v"(a[1]));
  asm("v_cvt_pk_bf16_f32 %0, %1, %2" : "=v"(r.u[1]) : "v"(a[2]), "v"(a[3]));
  asm("v_cvt_pk_bf16_f32 %0, %1, %2" : "=v"(r.u[2]) : "v"(b[0]), "v"(b[1]));
  asm("v_cvt_pk_bf16_f32 %0, %1, %2" : "=v"(r.u[3]) : "v"(b[2]), "v"(b[3]));
  return r.v;
}

// ---- DPP helpers ----
template<int CTRL>
__device__ __forceinline__ float dpp_add(float xx) {
  int y = __builtin_amdgcn_mov_dpp(__float_as_int(xx), CTRL, 0xF, 0xF, false);
  return xx + __int_as_float(y);
}
__device__ __forceinline__ float quad_sum4(float xx) {
  xx = dpp_add<0xB1>(xx);   // quad_perm xor1
  xx = dpp_add<0x4E>(xx);   // quad_perm xor2
  return xx;
}

// ---- bijective XCD-chunk swizzle (neutral but harmless; kept) ----
__device__ __forceinline__ void sgbg_map(int bid, int& sg, int& bg) {
  const int xcd = bid & 7, q = bid >> 3;
  sg = xcd*9 + (q % 9);
  bg = q / 9;
}

// ================== dispatch 1: pass1 (inline-cvt MFMA) + W-pack + x-pack ==================
//  [0, NP1B)            : pass1 — bf16-only 4n-K-packed MFMA on RAW W/x (inline cvt)
//  [NP1B, +NWB)         : W hi/lo split (linear)
//  [NP1B+NWB, +NTILES)  : x hi/lo split + 16x16 LDS transpose -> [n][b]
// pass1 blocks first: heaviest work starts earliest.
__global__ __launch_bounds__(256) void d1_all(
    const float* __restrict__ W, const float* __restrict__ x,
    short* __restrict__ WH, short* __restrict__ WL,
    short* __restrict__ XH, short* __restrict__ XL,
    float* __restrict__ P) {
  __shared__ f32x4 red[3*640];                     // 30 KB (x-pack aliases into it)
  const int bid = blockIdx.x, tid = threadIdx.x;

  if (bid < NP1B) {
    // ---- pass1: one MFMA covers 4 n (K-chunk c = n0+c); bf16-only ----
    const int sg = bid >> 4, bg = bid & 15;
    const int w = tid >> 6, l = tid & 63;
    const int bb = l & 15, c = l >> 4;
    const int b0 = bg * 16;
    const int n0 = sg*NPB1 + w*8;                  // wave covers 8 n = 2 packed groups

    f32x4 acc[N_OUT];
    const f32x4 zz = {0.f,0.f,0.f,0.f};
#pragma unroll
    for (int o=0;o<N_OUT;o++) acc[o] = zz;

#pragma unroll
    for (int grp=0; grp<2; ++grp) {
      const int nb = n0 + grp*4 + c;               // this lane's K-chunk n
      const bf16x8 bfrag = cvt8(&x[((size_t)(b0+bb)*N_IN + nb)*8]);
      const float* Wp = &W[(size_t)nb*1280 + bb*8];
#pragma unroll
      for (int o=0;o<N_OUT;o++) {
        const bf16x8 afrag = cvt8(Wp + o*128);
        acc[o] = __builtin_amdgcn_mfma_f32_16x16x32_bf16(afrag, bfrag, acc[o], 0,0,0);
      }
    }

    if (w) {
#pragma unroll
      for (int o=0;o<N_OUT;o++) red[(w-1)*640 + o*64 + l] = acc[o];
    }
    __syncthreads();
    if (!w) {
      float* Pp = &P[(size_t)sg*SN + (size_t)(b0 + bb)*OJ + c*4];
#pragma unroll
      for (int o=0;o<N_OUT;o++) {
        acc[o] += red[o*64+l] + red[640+o*64+l] + red[1280+o*64+l];
        *(f32x4*)&Pp[o*16] = acc[o];
      }
    }
  } else if (bid < NP1B + NWB) {
    // ---- W-pack (linear) ----
    const int t = (bid - NP1B)*256 + tid;
    bf16x8 vh, vl; split8(W + (size_t)t*8, vh, vl);
    ((bf16x8*)WH)[t] = vh; ((bf16x8*)WL)[t] = vl;
  } else {
    // ---- x-pack (LDS-transposed 16x16 tile -> [n][b]) ----
    bf16x8* TH = (bf16x8*)red;                     // 272 slots
    bf16x8* TL = TH + 272;
    const int tile = bid - NP1B - NWB;
    const int nt = tile >> 4, bt = tile & 15;
    const int nn = tid & 15, bb = tid >> 4;        // n fastest: coalesced reads
    bf16x8 vh, vl;
    split8(x + ((size_t)(bt*16+bb)*N_IN + nt*16+nn)*8, vh, vl);
    TH[nn*17 + bb] = vh; TL[nn*17 + bb] = vl;
    __syncthreads();
    const int bb2 = tid & 15, nn2 = tid >> 4;      // b fastest: coalesced writes
    const size_t o = (size_t)(nt*16+nn2)*B_ + bt*16 + bb2;
    ((bf16x8*)XH)[o] = TH[nn2*17 + bb2];
    ((bf16x8*)XL)[o] = TL[nn2*17 + bb2];
  }
}

// K-chunk split trick (pass2/3): A chunks [WH,WL,WH,WL], B [XH,XH,XL,XL]
// => exact (Wh+Wl)(xh+xl). C layout: col=lane&15=b, row=c*4+e=j.
__global__ __launch_bounds__(256) void caps_pass23(const short* __restrict__ WH,
                                                   const short* __restrict__ WL,
                                                   const short* __restrict__ XH,
                                                   const short* __restrict__ XL,
                                                   const float* __restrict__ veff,
                                                   float* __restrict__ P) {
  __shared__ f32x4 red[3*640];
  int sg, bg; sgbg_map(blockIdx.x, sg, bg);
  const int tid = threadIdx.x, w = tid >> 6, l = tid & 63;
  const int bb = l & 15, c = l >> 4;
  const int b0 = bg * 16;
  const int n0 = sg * NPB + w * NPW;
  const short* Abase = (c & 1)  ? WL : WH;
  const short* Bbase = (c >> 1) ? XL : XH;

  f32x4 vj[N_OUT], acc[N_OUT];
  const f32x4 zz = {0.f,0.f,0.f,0.f};
  const float* vp = &veff[(size_t)(b0+bb)*OJ + c*4];
#pragma unroll
  for (int o=0;o<N_OUT;o++) { vj[o] = *(const f32x4*)&vp[o*16]; acc[o] = zz; }

  for (int nn=0; nn<NPW; ++nn) {
    const int n = n0 + nn;
    const bf16x8 bfrag = *(const bf16x8*)&Bbase[((size_t)n*B_ + b0 + bb)*8];
    const short* Ap = &Abase[(size_t)n*1280 + bb*8];
    f32x4 u[N_OUT];
#pragma unroll
    for (int o=0;o<N_OUT;o++) {
      const bf16x8 afrag = *(const bf16x8*)&Ap[o*128];
      u[o] = __builtin_amdgcn_mfma_f32_16x16x32_bf16(afrag, bfrag, zz, 0,0,0);
    }
    float ez[N_OUT], Z = 0.f;
#pragma unroll
    for (int o=0;o<N_OUT;o++) {
      float t = u[o][0]*vj[o][0] + u[o][1]*vj[o][1]
              + u[o][2]*vj[o][2] + u[o][3]*vj[o][3];
      t += __shfl_xor(t, 16);
      t += __shfl_xor(t, 32);
      ez[o] = exp2f(t);                // veff already in log2 domain
      Z += ez[o];
    }
    const float invZ = __builtin_amdgcn_rcpf(Z);
#pragma unroll
    for (int o=0;o<N_OUT;o++) acc[o] += (ez[o] * invZ) * u[o];
  }

  if (w) {
#pragma unroll
    for (int o=0;o<N_OUT;o++) red[(w-1)*640 + o*64 + l] = acc[o];
  }
  __syncthreads();
  if (!w) {
    float* Pp = &P[(size_t)sg*SN + (size_t)(b0 + bb)*OJ + c*4];
#pragma unroll
    for (int o=0;o<N_OUT;o++) {
      acc[o] += red[o*64+l] + red[640+o*64+l] + red[1280+o*64+l];
      *(f32x4*)&Pp[o*16] = acc[o];
    }
  }
}

// ---- vectorized finish: f32x4 per thread (one j-quad), quad_perm reduce ----
template<int GC>
__global__ __launch_bounds__(256) void caps_finish(const float* __restrict__ P, float scale,
                                                   const float* __restrict__ vprev,
                                                   float* __restrict__ vout, float lscale) {
  const int e0 = (blockIdx.x*256 + threadIdx.x)*4;
  f32x4 t = {0.f,0.f,0.f,0.f};
#pragma unroll 8
  for (int g=0; g<GC; ++g) t += *(const f32x4*)&P[(size_t)g*SN + e0];
  t *= scale;
  const float sq = quad_sum4(t[0]*t[0] + t[1]*t[1] + t[2]*t[2] + t[3]*t[3]);
  const float k = (sq/(1.f+sq)) * rsqrtf(sq + 1e-8f) * lscale;
  f32x4 v = t * k;
  if (vprev != nullptr) v += *(const f32x4*)&vprev[e0];
  *(f32x4*)&vout[e0] = v;
}

extern "C" void kernel_launch(void* const* d_in, const int* in_sizes, int n_in,
                              void* d_out, int out_size, void* d_ws, size_t ws_size,
                              hipStream_t stream) {
  const float* x = (const float*)d_in[0];   // (256,1152,8)
  const float* W = (const float*)d_in[1];   // (1,1152,10,16,8)
  float* out = (float*)d_out;               // (256,10,16)

  float* P   = (float*)d_ws;                // 72*SN floats = 11.8 MB (pass1 uses 36)
  float* v1  = P  + (size_t)NSG*SN;         // stored * log2e
  float* v12 = v1 + SN;                     // stored * log2e
  short* WH = (short*)(v12 + SN);
  short* WL = WH + (size_t)NW_ELEMS*8;
  short* XH = WL + (size_t)NW_ELEMS*8;
  short* XL = XH + (size_t)NX_ELEMS*8;      // total ws ~= 27.5 MB

  // d1: pass1 (raw f32 via inline cvt, MFMA-shaped) + W-pack + x-pack
  d1_all<<<NP1B + NWB + NTILES, 256, 0, stream>>>(W, x, WH, WL, XH, XL, P);
  // d2: v1 = squash(0.1*s1)*log2e
  caps_finish<NSG1><<<SN/1024, 256, 0, stream>>>(P, 0.1f, nullptr, v1, LOG2E);
  // d3: logits = u.v1 -> P[72]
  caps_pass23<<<NPASSB, 256, 0, stream>>>(WH, WL, XH, XL, v1, P);
  // d4: v12 = v1 + squash(s2)*log2e
  caps_finish<NSG><<<SN/1024, 256, 0, stream>>>(P, 1.0f, v1, v12, LOG2E);
  // d5: logits = u.v12 -> P[72]
  caps_pass23<<<NPASSB, 256, 0, stream>>>(WH, WL, XH, XL, v12, P);
  // d6: out = squash(s3)
  caps_finish<NSG><<<SN/1024, 256, 0, stream>>>(P, 1.0f, nullptr, out, 1.0f);
}